// Round 1
// baseline (420.332 us; speedup 1.0000x reference)
//
#include <hip/hip_runtime.h>

// units2indices: pack groups of num_bits bipolar {-1,+1} fp32 values into
// base-2 indices (first element of each group is the MSB).
//
// Memory-bound streaming kernel: 320 MB read + 32 MB write => ~56 us floor
// at 6.3 TB/s. Fast path: num_bits==10, 2 groups/thread = 20 floats = 80 B
// => five aligned float4 loads per thread, one int2 store.

__device__ __forceinline__ int bit_of(float x) {
    // bipolar +1.0 -> 1, -1.0 -> 0 ; exact sign test
    return x > 0.0f ? 1 : 0;
}

__global__ __launch_bounds__(256) void pack10_pair_kernel(
    const float* __restrict__ in, int* __restrict__ out, int num_pairs)
{
    int t = blockIdx.x * blockDim.x + threadIdx.x;
    if (t >= num_pairs) return;

    // thread t covers floats [20t, 20t+20): byte offset 80t, 16B-aligned
    const float4* p = reinterpret_cast<const float4*>(in + (size_t)t * 20u);
    float4 v0 = p[0];
    float4 v1 = p[1];
    float4 v2 = p[2];
    float4 v3 = p[3];
    float4 v4 = p[4];

    int i0 = (bit_of(v0.x) << 9) | (bit_of(v0.y) << 8) | (bit_of(v0.z) << 7) | (bit_of(v0.w) << 6)
           | (bit_of(v1.x) << 5) | (bit_of(v1.y) << 4) | (bit_of(v1.z) << 3) | (bit_of(v1.w) << 2)
           | (bit_of(v2.x) << 1) |  bit_of(v2.y);
    int i1 = (bit_of(v2.z) << 9) | (bit_of(v2.w) << 8) | (bit_of(v3.x) << 7) | (bit_of(v3.y) << 6)
           | (bit_of(v3.z) << 5) | (bit_of(v3.w) << 4) | (bit_of(v4.x) << 3) | (bit_of(v4.y) << 2)
           | (bit_of(v4.z) << 1) |  bit_of(v4.w);

    reinterpret_cast<int2*>(out)[t] = make_int2(i0, i1);
}

// Fallback for any other num_bits (correctness safety net; not the bench path).
__global__ __launch_bounds__(256) void pack_generic_kernel(
    const float* __restrict__ in, int* __restrict__ out, int n_groups, int num_bits)
{
    int t = blockIdx.x * blockDim.x + threadIdx.x;
    if (t >= n_groups) return;
    const float* g = in + (size_t)t * (size_t)num_bits;
    int idx = 0;
    for (int j = 0; j < num_bits; ++j)
        idx = (idx << 1) | (g[j] > 0.0f ? 1 : 0);
    out[t] = idx;
}

extern "C" void kernel_launch(void* const* d_in, const int* in_sizes, int n_in,
                              void* d_out, int out_size, void* d_ws, size_t ws_size,
                              hipStream_t stream)
{
    const float* in = (const float*)d_in[0];
    int* out = (int*)d_out;
    const int n = in_sizes[0];
    const int num_bits = (out_size > 0) ? (n / out_size) : 10;

    if (num_bits == 10 && (out_size & 1) == 0) {
        const int num_pairs = out_size >> 1;      // 4,000,000
        const int block = 256;
        const int grid = (num_pairs + block - 1) / block;  // 15625
        pack10_pair_kernel<<<grid, block, 0, stream>>>(in, out, num_pairs);
    } else {
        const int block = 256;
        const int grid = (out_size + block - 1) / block;
        pack_generic_kernel<<<grid, block, 0, stream>>>(in, out, out_size, num_bits);
    }
}